// Round 1
// baseline (157.117 us; speedup 1.0000x reference)
//
#include <hip/hip_runtime.h>
#include <math.h>

#define CELU_ALPHA 3.0f

__device__ __forceinline__ float celu3(float x) {
    // overflow-safe: max(x,0) + a*expm1(min(x,0)/a)
    return fmaxf(x, 0.0f) + CELU_ALPHA * expm1f(fminf(x, 0.0f) * (1.0f / CELU_ALPHA));
}

__device__ __forceinline__ float wave_sum64(float v) {
#pragma unroll
    for (int off = 32; off > 0; off >>= 1) v += __shfl_xor(v, off, 64);
    return v;
}

// ---- CSR build -------------------------------------------------------------

__global__ void hist_kernel(const int* __restrict__ seg, int* __restrict__ counts, int E) {
    int i = blockIdx.x * blockDim.x + threadIdx.x;
    int stride = gridDim.x * blockDim.x;
    for (; i < E; i += stride) atomicAdd(&counts[seg[i]], 1);
}

// single block of 1024; N <= 1024*32
__global__ void scan_kernel(const int* __restrict__ counts, int* __restrict__ offsets,
                            int* __restrict__ cursor, int N) {
    __shared__ int part[1024];
    int tid = threadIdx.x;
    int per = (N + 1023) / 1024;
    int base = tid * per;
    int local[32];
    int sum = 0;
    for (int i = 0; i < per; ++i) {
        int idx = base + i;
        local[i] = sum;
        if (idx < N) sum += counts[idx];
    }
    part[tid] = sum;
    __syncthreads();
    for (int off = 1; off < 1024; off <<= 1) {
        int v = 0;
        if (tid >= off) v = part[tid - off];
        __syncthreads();
        if (tid >= off) part[tid] += v;
        __syncthreads();
    }
    int excl = (tid == 0) ? 0 : part[tid - 1];
    for (int i = 0; i < per; ++i) {
        int idx = base + i;
        if (idx < N) {
            int o = excl + local[i];
            offsets[idx] = o;
            cursor[idx] = o;
        }
    }
    if (tid == 1023) offsets[N] = part[1023];
}

__global__ void scatter_kernel(const int* __restrict__ seg, int* __restrict__ cursor,
                               int* __restrict__ elist, int E) {
    int i = blockIdx.x * blockDim.x + threadIdx.x;
    int stride = gridDim.x * blockDim.x;
    for (; i < E; i += stride) {
        int s = seg[i];
        int pos = atomicAdd(&cursor[s], 1);
        elist[pos] = i;
    }
}

// ---- main aggregation: one wave (64 lanes) per node ------------------------

__global__ __launch_bounds__(256) void agg_kernel(
    const float* __restrict__ feat,   // [N,64]
    const float* __restrict__ meta,   // [E,64]
    const float* __restrict__ w1,     // [4,64]
    const float* __restrict__ w2,     // [4,64]
    const int* __restrict__ offsets,  // [N+1]
    const int* __restrict__ elist,    // [E]
    float* __restrict__ out,          // [N, 4*64]
    int N)
{
    int lane = threadIdx.x & 63;
    int wv = threadIdx.x >> 6;
    int n = blockIdx.x * 4 + wv;
    if (n >= N) return;

    float w1v[4], w2v[4];
#pragma unroll
    for (int h = 0; h < 4; ++h) {
        w1v[h] = w1[h * 64 + lane];
        w2v[h] = w2[h * 64 + lane];
    }

    // a1[n,h] = celu(features[n] . attn1_w[h])
    float f = feat[(long)n * 64 + lane];
    float a1[4];
#pragma unroll
    for (int h = 0; h < 4; ++h) a1[h] = celu3(wave_sum64(f * w1v[h]));

    int beg = offsets[n];
    int end = offsets[n + 1];

    float m[4], s[4], acc[4];
#pragma unroll
    for (int h = 0; h < 4; ++h) { m[h] = -INFINITY; s[h] = 0.0f; acc[h] = 0.0f; }

    for (int e = beg; e < end; ++e) {
        int eid = elist[e];
        float x = meta[(long)eid * 64 + lane];
        float eft = celu3(x);
#pragma unroll
        for (int h = 0; h < 4; ++h) {
            float a2 = wave_sum64(eft * w2v[h]);
            float a = celu3(a1[h] + a2);
            float nm = fmaxf(m[h], a);
            float scale = __expf(m[h] - nm);   // first edge: exp(-inf)=0
            float p = __expf(a - nm);
            s[h] = s[h] * scale + p;
            acc[h] = acc[h] * scale + p * eft;
            m[h] = nm;
        }
    }

#pragma unroll
    for (int h = 0; h < 4; ++h) {
        float r = (s[h] > 0.0f) ? (acc[h] / s[h]) : 0.0f;
        out[(long)n * 256 + h * 64 + lane] = celu3(r);
    }
}

// ---- launch ----------------------------------------------------------------

extern "C" void kernel_launch(void* const* d_in, const int* in_sizes, int n_in,
                              void* d_out, int out_size, void* d_ws, size_t ws_size,
                              hipStream_t stream)
{
    const float* feat = (const float*)d_in[0];
    const float* meta = (const float*)d_in[1];
    const float* w1   = (const float*)d_in[2];
    const float* w2   = (const float*)d_in[3];
    const int*   seg  = (const int*)d_in[4];
    float* out = (float*)d_out;

    int N = in_sizes[0] / 64;
    int E = in_sizes[4];

    int* ws = (int*)d_ws;
    int* counts  = ws;              // N
    int* offsets = ws + N;          // N+1
    int* cursor  = ws + 2 * N + 1;  // N
    int* elist   = ws + 3 * N + 1;  // E

    hipMemsetAsync(counts, 0, (size_t)N * sizeof(int), stream);
    hist_kernel<<<512, 256, 0, stream>>>(seg, counts, E);
    scan_kernel<<<1, 1024, 0, stream>>>(counts, offsets, cursor, N);
    scatter_kernel<<<512, 256, 0, stream>>>(seg, cursor, elist, E);
    agg_kernel<<<(N + 3) / 4, 256, 0, stream>>>(feat, meta, w1, w2, offsets, elist, out, N);
}

// Round 2
// 124.766 us; speedup vs baseline: 1.2593x; 1.2593x over previous
//
#include <hip/hip_runtime.h>
#include <math.h>

__device__ __forceinline__ float celu3(float x) {
    // celu(x,3) = max(x,0) + 3*(exp(min(x,0)/3)-1); __expf accurate enough (abs err ~1e-6)
    return fmaxf(x, 0.0f) + 3.0f * (__expf(fminf(x, 0.0f) * (1.0f / 3.0f)) - 1.0f);
}

__device__ __forceinline__ float wave_sum64(float v) {
#pragma unroll
    for (int off = 32; off > 0; off >>= 1) v += __shfl_xor(v, off, 64);
    return v;
}
__device__ __forceinline__ float wave_max64(float v) {
#pragma unroll
    for (int off = 32; off > 0; off >>= 1) v = fmaxf(v, __shfl_xor(v, off, 64));
    return v;
}

// ---- CSR build -------------------------------------------------------------

__global__ void hist_kernel(const int* __restrict__ seg, int* __restrict__ counts, int E) {
    int i = blockIdx.x * blockDim.x + threadIdx.x;
    int stride = gridDim.x * blockDim.x;
    for (; i < E; i += stride) atomicAdd(&counts[seg[i]], 1);
}

__global__ void scan_kernel(const int* __restrict__ counts, int* __restrict__ offsets,
                            int* __restrict__ cursor, int N) {
    __shared__ int part[1024];
    int tid = threadIdx.x;
    int per = (N + 1023) / 1024;
    int base = tid * per;
    int local[32];
    int sum = 0;
    for (int i = 0; i < per; ++i) {
        int idx = base + i;
        local[i] = sum;
        if (idx < N) sum += counts[idx];
    }
    part[tid] = sum;
    __syncthreads();
    for (int off = 1; off < 1024; off <<= 1) {
        int v = 0;
        if (tid >= off) v = part[tid - off];
        __syncthreads();
        if (tid >= off) part[tid] += v;
        __syncthreads();
    }
    int excl = (tid == 0) ? 0 : part[tid - 1];
    for (int i = 0; i < per; ++i) {
        int idx = base + i;
        if (idx < N) {
            int o = excl + local[i];
            offsets[idx] = o;
            cursor[idx] = o;
        }
    }
    if (tid == 1023) offsets[N] = part[1023];
}

__global__ void scatter_kernel(const int* __restrict__ seg, int* __restrict__ cursor,
                               int* __restrict__ elist, int* __restrict__ rank, int E) {
    int i = blockIdx.x * blockDim.x + threadIdx.x;
    int stride = gridDim.x * blockDim.x;
    for (; i < E; i += stride) {
        int s = seg[i];
        int pos = atomicAdd(&cursor[s], 1);
        elist[pos] = i;
        rank[i] = pos;
    }
}

// ---- a1[n,h] = celu(feat[n] . w1[h]) --------------------------------------

__global__ __launch_bounds__(256) void a1_kernel(
    const float* __restrict__ feat, const float* __restrict__ w1,
    float* __restrict__ a1, int N)
{
    int lane = threadIdx.x & 63;
    int wv = threadIdx.x >> 6;
    int n = blockIdx.x * 4 + wv;
    if (n >= N) return;
    float f = feat[(long)n * 64 + lane];
    float s[4];
#pragma unroll
    for (int h = 0; h < 4; ++h) s[h] = wave_sum64(f * w1[h * 64 + lane]);
    if (lane < 4) a1[n * 4 + lane] = celu3(s[lane]);
}

// ---- edge pass: a_csr[rank[e]][h] = celu(a1[seg[e],h] + celu(meta[e]).w2[h])

__global__ __launch_bounds__(256) void edge_kernel(
    const float* __restrict__ meta, const float* __restrict__ w2,
    const float* __restrict__ a1, const int* __restrict__ seg,
    const int* __restrict__ rank, float* __restrict__ a_csr, int E)
{
    __shared__ float sm[64][68];      // celu(meta) tile, padded (68*4B, 16B-aligned rows)
    __shared__ float w2s[4][64];
    int t = threadIdx.x;
    w2s[t >> 6][t & 63] = w2[t];      // 256 == 4*64

    long e0 = (long)blockIdx.x * 64;
    const float4* msrc = (const float4*)meta + e0 * 16;
    int nval = (int)min((long)64, (long)E - e0);   // edges in this tile

#pragma unroll
    for (int k = 0; k < 4; ++k) {
        int j = t + k * 256;           // float4 index within tile, 0..1023
        int e_loc = j >> 4, d4 = j & 15;
        if (e_loc < nval) {
            float4 v = msrc[j];
            float4 c;
            c.x = celu3(v.x); c.y = celu3(v.y); c.z = celu3(v.z); c.w = celu3(v.w);
            *(float4*)&sm[e_loc][d4 * 4] = c;
        }
    }
    __syncthreads();

    int e_loc = t >> 2, h = t & 3;
    if (e_loc >= nval) return;
    long e = e0 + e_loc;
    const float4* row = (const float4*)&sm[e_loc][0];
    const float4* wr  = (const float4*)&w2s[h][0];
    float acc = 0.0f;
#pragma unroll
    for (int d4 = 0; d4 < 16; ++d4) {
        float4 v = row[d4], w = wr[d4];
        acc += v.x * w.x + v.y * w.y + v.z * w.z + v.w * w.w;
    }
    float a = celu3(a1[seg[e] * 4 + h] + acc);
    a_csr[(long)rank[e] * 4 + h] = a;
}

// ---- softmax + weighted aggregate: one wave per node -----------------------

__global__ __launch_bounds__(256) void agg2_kernel(
    const float* __restrict__ meta, const int* __restrict__ offsets,
    const int* __restrict__ elist, const float4* __restrict__ a_csr,
    float* __restrict__ out, int N)
{
    int lane = threadIdx.x & 63;
    int wv = threadIdx.x >> 6;
    int n = blockIdx.x * 4 + wv;
    if (n >= N) return;

    int beg = offsets[n];
    int end = offsets[n + 1];

    float acc0 = 0.f, acc1 = 0.f, acc2 = 0.f, acc3 = 0.f;
    float4 rden = {0.f, 0.f, 0.f, 0.f};

    if (beg < end) {
        // phase 1: segment max per head (lane-parallel over edges)
        float4 m = {-INFINITY, -INFINITY, -INFINITY, -INFINITY};
        for (int c = beg; c < end; c += 64) {
            int idx = c + lane;
            if (idx < end) {
                float4 av = a_csr[idx];
                m.x = fmaxf(m.x, av.x); m.y = fmaxf(m.y, av.y);
                m.z = fmaxf(m.z, av.z); m.w = fmaxf(m.w, av.w);
            }
        }
        m.x = wave_max64(m.x); m.y = wave_max64(m.y);
        m.z = wave_max64(m.z); m.w = wave_max64(m.w);

        // phase 2: unnormalized accumulate (max known -> no rescale chain)
        float4 den = {0.f, 0.f, 0.f, 0.f};
        for (int j = beg; j < end; ++j) {
            float4 av = a_csr[j];              // wave-uniform load, L1/L2-hot
            float e0 = __expf(av.x - m.x), e1 = __expf(av.y - m.y);
            float e2 = __expf(av.z - m.z), e3 = __expf(av.w - m.w);
            den.x += e0; den.y += e1; den.z += e2; den.w += e3;
            int eid = elist[j];                // wave-uniform
            float eft = celu3(meta[(long)eid * 64 + lane]);  // coalesced 256B
            acc0 = fmaf(e0, eft, acc0);
            acc1 = fmaf(e1, eft, acc1);
            acc2 = fmaf(e2, eft, acc2);
            acc3 = fmaf(e3, eft, acc3);
        }
        rden.x = 1.0f / den.x; rden.y = 1.0f / den.y;
        rden.z = 1.0f / den.z; rden.w = 1.0f / den.w;
    }

    long ob = (long)n * 256 + lane;
    out[ob]       = celu3(acc0 * rden.x);
    out[ob + 64]  = celu3(acc1 * rden.y);
    out[ob + 128] = celu3(acc2 * rden.z);
    out[ob + 192] = celu3(acc3 * rden.w);
}

// ---- launch ----------------------------------------------------------------

extern "C" void kernel_launch(void* const* d_in, const int* in_sizes, int n_in,
                              void* d_out, int out_size, void* d_ws, size_t ws_size,
                              hipStream_t stream)
{
    const float* feat = (const float*)d_in[0];
    const float* meta = (const float*)d_in[1];
    const float* w1   = (const float*)d_in[2];
    const float* w2   = (const float*)d_in[3];
    const int*   seg  = (const int*)d_in[4];
    float* out = (float*)d_out;

    int N = in_sizes[0] / 64;
    int E = in_sizes[4];

    // workspace layout (a_csr first for 16B alignment)
    float4* a_csr = (float4*)d_ws;                 // E float4
    float*  a1    = (float*)(a_csr + E);           // N*4
    int* counts   = (int*)(a1 + (size_t)N * 4);    // N
    int* offsets  = counts + N;                    // N+1
    int* cursor   = offsets + N + 1;               // N
    int* rank     = cursor + N;                    // E
    int* elist    = rank + E;                      // E

    hipMemsetAsync(counts, 0, (size_t)N * sizeof(int), stream);
    hist_kernel<<<512, 256, 0, stream>>>(seg, counts, E);
    scan_kernel<<<1, 1024, 0, stream>>>(counts, offsets, cursor, N);
    scatter_kernel<<<512, 256, 0, stream>>>(seg, cursor, elist, rank, E);
    a1_kernel<<<(N + 3) / 4, 256, 0, stream>>>(feat, w1, a1, N);
    edge_kernel<<<(E + 63) / 64, 256, 0, stream>>>(meta, w2, a1, seg, rank, (float*)a_csr, E);
    agg2_kernel<<<(N + 3) / 4, 256, 0, stream>>>(meta, offsets, elist, a_csr, out, N);
}

// Round 3
// 109.615 us; speedup vs baseline: 1.4334x; 1.1382x over previous
//
#include <hip/hip_runtime.h>
#include <math.h>

__device__ __forceinline__ float celu3(float x) {
    // celu(x,3) = max(x,0) + 3*(exp(min(x,0)/3)-1)
    return fmaxf(x, 0.0f) + 3.0f * (__expf(fminf(x, 0.0f) * (1.0f / 3.0f)) - 1.0f);
}

__device__ __forceinline__ float wave_sum64(float v) {
#pragma unroll
    for (int off = 32; off > 0; off >>= 1) v += __shfl_xor(v, off, 64);
    return v;
}
__device__ __forceinline__ float wave_max64(float v) {
#pragma unroll
    for (int off = 32; off > 0; off >>= 1) v = fmaxf(v, __shfl_xor(v, off, 64));
    return v;
}
__device__ __forceinline__ float bcast_f(float v, int lane) {
    return __int_as_float(__builtin_amdgcn_readlane(__float_as_int(v), lane));
}

// ---- CSR hist + a1 (fused) -------------------------------------------------

__global__ __launch_bounds__(256) void hist_a1_kernel(
    const int* __restrict__ seg, int* __restrict__ counts, int E,
    const float* __restrict__ feat, const float* __restrict__ w1,
    float* __restrict__ a1, int N)
{
    int nblk_a1 = (N + 3) / 4;
    if ((int)blockIdx.x < nblk_a1) {
        int lane = threadIdx.x & 63;
        int wv = threadIdx.x >> 6;
        int n = blockIdx.x * 4 + wv;
        if (n >= N) return;
        float f = feat[(long)n * 64 + lane];
        float s[4];
#pragma unroll
        for (int h = 0; h < 4; ++h) s[h] = wave_sum64(f * w1[h * 64 + lane]);
        if (lane < 4) a1[n * 4 + lane] = celu3(s[lane]);
    } else {
        int i = (blockIdx.x - nblk_a1) * blockDim.x + threadIdx.x;
        int stride = 512 * blockDim.x;
        for (; i < E; i += stride) atomicAdd(&counts[seg[i]], 1);
    }
}

__global__ void scan_kernel(const int* __restrict__ counts, int* __restrict__ offsets,
                            int* __restrict__ cursor, int N) {
    __shared__ int part[1024];
    int tid = threadIdx.x;
    int per = (N + 1023) / 1024;
    int base = tid * per;
    int local[32];
    int sum = 0;
    for (int i = 0; i < per; ++i) {
        int idx = base + i;
        local[i] = sum;
        if (idx < N) sum += counts[idx];
    }
    part[tid] = sum;
    __syncthreads();
    for (int off = 1; off < 1024; off <<= 1) {
        int v = 0;
        if (tid >= off) v = part[tid - off];
        __syncthreads();
        if (tid >= off) part[tid] += v;
        __syncthreads();
    }
    int excl = (tid == 0) ? 0 : part[tid - 1];
    for (int i = 0; i < per; ++i) {
        int idx = base + i;
        if (idx < N) {
            int o = excl + local[i];
            offsets[idx] = o;
            cursor[idx] = o;
        }
    }
    if (tid == 1023) offsets[N] = part[1023];
}

__global__ void scatter_kernel(const int* __restrict__ seg, int* __restrict__ cursor,
                               int* __restrict__ elist, int* __restrict__ rank, int E) {
    int i = blockIdx.x * blockDim.x + threadIdx.x;
    int stride = gridDim.x * blockDim.x;
    for (; i < E; i += stride) {
        int s = seg[i];
        int pos = atomicAdd(&cursor[s], 1);
        elist[pos] = i;
        rank[i] = pos;
    }
}

// ---- edge pass: a_csr[rank[e]][h] = celu(a1[seg[e],h] + celu(meta[e]).w2[h])

__global__ __launch_bounds__(256) void edge_kernel(
    const float* __restrict__ meta, const float* __restrict__ w2,
    const float* __restrict__ a1, const int* __restrict__ seg,
    const int* __restrict__ rank, float* __restrict__ a_csr, int E)
{
    __shared__ float sm[64][68];      // celu(meta) tile, padded
    __shared__ float w2s[4][64];
    int t = threadIdx.x;
    w2s[t >> 6][t & 63] = w2[t];      // 256 == 4*64

    long e0 = (long)blockIdx.x * 64;
    const float4* msrc = (const float4*)meta + e0 * 16;
    int nval = (int)min((long)64, (long)E - e0);

#pragma unroll
    for (int k = 0; k < 4; ++k) {
        int j = t + k * 256;
        int e_loc = j >> 4, d4 = j & 15;
        if (e_loc < nval) {
            float4 v = msrc[j];
            float4 c;
            c.x = celu3(v.x); c.y = celu3(v.y); c.z = celu3(v.z); c.w = celu3(v.w);
            *(float4*)&sm[e_loc][d4 * 4] = c;
        }
    }
    __syncthreads();

    int e_loc = t >> 2, h = t & 3;
    if (e_loc >= nval) return;
    long e = e0 + e_loc;
    const float4* row = (const float4*)&sm[e_loc][0];
    const float4* wr  = (const float4*)&w2s[h][0];
    float acc = 0.0f;
#pragma unroll
    for (int d4 = 0; d4 < 16; ++d4) {
        float4 v = row[d4], w = wr[d4];
        acc += v.x * w.x + v.y * w.y + v.z * w.z + v.w * w.w;
    }
    float a = celu3(a1[seg[e] * 4 + h] + acc);
    a_csr[(long)rank[e] * 4 + h] = a;
}

// ---- softmax + weighted aggregate: one wave per node -----------------------

__global__ __launch_bounds__(256) void agg2_kernel(
    const float* __restrict__ meta, const int* __restrict__ offsets,
    const int* __restrict__ elist, const float4* __restrict__ a_csr,
    float* __restrict__ out, int N)
{
    int lane = threadIdx.x & 63;
    int wv = threadIdx.x >> 6;
    int n = blockIdx.x * 4 + wv;
    if (n >= N) return;

    int beg = offsets[n];
    int end = offsets[n + 1];
    int cnt = end - beg;

    float acc0 = 0.f, acc1 = 0.f, acc2 = 0.f, acc3 = 0.f;

    if (cnt > 0 && cnt <= 64) {
        // ---- fast path: lane = edge ----
        bool valid = lane < cnt;
        int idx = beg + lane;
        int eid_l = 0;
        float4 av = {-INFINITY, -INFINITY, -INFINITY, -INFINITY};
        if (valid) {
            eid_l = elist[idx];
            av = a_csr[idx];
        }
        float4 m;
        m.x = wave_max64(av.x); m.y = wave_max64(av.y);
        m.z = wave_max64(av.z); m.w = wave_max64(av.w);

        float e0 = valid ? __expf(av.x - m.x) : 0.f;
        float e1 = valid ? __expf(av.y - m.y) : 0.f;
        float e2 = valid ? __expf(av.z - m.z) : 0.f;
        float e3 = valid ? __expf(av.w - m.w) : 0.f;

        float4 den;
        den.x = wave_sum64(e0); den.y = wave_sum64(e1);
        den.z = wave_sum64(e2); den.w = wave_sum64(e3);

        // pre-normalized attention weights, one per lane(=edge)
        float at0 = e0 * (1.0f / den.x);
        float at1 = e1 * (1.0f / den.y);
        float at2 = e2 * (1.0f / den.z);
        float at3 = e3 * (1.0f / den.w);

#pragma unroll 4
        for (int j = 0; j < cnt; ++j) {
            int eid = __builtin_amdgcn_readlane(eid_l, j);
            float b0 = bcast_f(at0, j);
            float b1 = bcast_f(at1, j);
            float b2 = bcast_f(at2, j);
            float b3 = bcast_f(at3, j);
            float eft = celu3(meta[(long)eid * 64 + lane]);
            acc0 = fmaf(b0, eft, acc0);
            acc1 = fmaf(b1, eft, acc1);
            acc2 = fmaf(b2, eft, acc2);
            acc3 = fmaf(b3, eft, acc3);
        }
    } else if (cnt > 64) {
        // ---- fallback: streaming two-phase ----
        float4 m = {-INFINITY, -INFINITY, -INFINITY, -INFINITY};
        for (int c = beg; c < end; c += 64) {
            int idx = c + lane;
            if (idx < end) {
                float4 av = a_csr[idx];
                m.x = fmaxf(m.x, av.x); m.y = fmaxf(m.y, av.y);
                m.z = fmaxf(m.z, av.z); m.w = fmaxf(m.w, av.w);
            }
        }
        m.x = wave_max64(m.x); m.y = wave_max64(m.y);
        m.z = wave_max64(m.z); m.w = wave_max64(m.w);

        float4 den = {0.f, 0.f, 0.f, 0.f};
        for (int j = beg; j < end; ++j) {
            float4 av = a_csr[j];
            float e0 = __expf(av.x - m.x), e1 = __expf(av.y - m.y);
            float e2 = __expf(av.z - m.z), e3 = __expf(av.w - m.w);
            den.x += e0; den.y += e1; den.z += e2; den.w += e3;
            int eid = elist[j];
            float eft = celu3(meta[(long)eid * 64 + lane]);
            acc0 = fmaf(e0, eft, acc0);
            acc1 = fmaf(e1, eft, acc1);
            acc2 = fmaf(e2, eft, acc2);
            acc3 = fmaf(e3, eft, acc3);
        }
        acc0 *= (1.0f / den.x); acc1 *= (1.0f / den.y);
        acc2 *= (1.0f / den.z); acc3 *= (1.0f / den.w);
    }

    long ob = (long)n * 256 + lane;
    out[ob]       = celu3(acc0);
    out[ob + 64]  = celu3(acc1);
    out[ob + 128] = celu3(acc2);
    out[ob + 192] = celu3(acc3);
}

// ---- launch ----------------------------------------------------------------

extern "C" void kernel_launch(void* const* d_in, const int* in_sizes, int n_in,
                              void* d_out, int out_size, void* d_ws, size_t ws_size,
                              hipStream_t stream)
{
    const float* feat = (const float*)d_in[0];
    const float* meta = (const float*)d_in[1];
    const float* w1   = (const float*)d_in[2];
    const float* w2   = (const float*)d_in[3];
    const int*   seg  = (const int*)d_in[4];
    float* out = (float*)d_out;

    int N = in_sizes[0] / 64;
    int E = in_sizes[4];

    float4* a_csr = (float4*)d_ws;                 // E float4
    float*  a1    = (float*)(a_csr + E);           // N*4
    int* counts   = (int*)(a1 + (size_t)N * 4);    // N
    int* offsets  = counts + N;                    // N+1
    int* cursor   = offsets + N + 1;               // N
    int* rank     = cursor + N;                    // E
    int* elist    = rank + E;                      // E

    int nblk_a1 = (N + 3) / 4;

    hipMemsetAsync(counts, 0, (size_t)N * sizeof(int), stream);
    hist_a1_kernel<<<nblk_a1 + 512, 256, 0, stream>>>(seg, counts, E, feat, w1, a1, N);
    scan_kernel<<<1, 1024, 0, stream>>>(counts, offsets, cursor, N);
    scatter_kernel<<<512, 256, 0, stream>>>(seg, cursor, elist, rank, E);
    edge_kernel<<<(E + 63) / 64, 256, 0, stream>>>(meta, w2, a1, seg, rank, (float*)a_csr, E);
    agg2_kernel<<<(N + 3) / 4, 256, 0, stream>>>(meta, offsets, elist, a_csr, out, N);
}

// Round 4
// 90.114 us; speedup vs baseline: 1.7435x; 1.2164x over previous
//
#include <hip/hip_runtime.h>
#include <math.h>

__device__ __forceinline__ float celu3(float x) {
    // celu(x,3) = max(x,0) + 3*(exp(min(x,0)/3)-1)
    return fmaxf(x, 0.0f) + 3.0f * (__expf(fminf(x, 0.0f) * (1.0f / 3.0f)) - 1.0f);
}

__device__ __forceinline__ float wave_sum64(float v) {
#pragma unroll
    for (int off = 32; off > 0; off >>= 1) v += __shfl_xor(v, off, 64);
    return v;
}
__device__ __forceinline__ float wave_max64(float v) {
#pragma unroll
    for (int off = 32; off > 0; off >>= 1) v = fmaxf(v, __shfl_xor(v, off, 64));
    return v;
}
__device__ __forceinline__ float bcast_f(float v, int lane) {
    return __int_as_float(__builtin_amdgcn_readlane(__float_as_int(v), lane));
}

// ---- zero counts (rocclr fillBuffer costs ~40us in-graph; ours ~1.5us) -----

__global__ __launch_bounds__(256) void zero_kernel(int* __restrict__ p, int n) {
    int i = blockIdx.x * 256 + threadIdx.x;
    if (i < n) p[i] = 0;
}

// ---- rank/hist + a1 (fused) ------------------------------------------------
// rank[e] = within-segment arrival order; counts[n] = segment size

__global__ __launch_bounds__(256) void rank_hist_a1_kernel(
    const int* __restrict__ seg, int* __restrict__ counts, int* __restrict__ rank, int E,
    const float* __restrict__ feat, const float* __restrict__ w1,
    float* __restrict__ a1, int N)
{
    int nblk_a1 = (N + 3) / 4;
    if ((int)blockIdx.x < nblk_a1) {
        int lane = threadIdx.x & 63;
        int wv = threadIdx.x >> 6;
        int n = blockIdx.x * 4 + wv;
        if (n >= N) return;
        float f = feat[(long)n * 64 + lane];
        float s[4];
#pragma unroll
        for (int h = 0; h < 4; ++h) s[h] = wave_sum64(f * w1[h * 64 + lane]);
        if (lane < 4) a1[n * 4 + lane] = celu3(s[lane]);
    } else {
        int i = (blockIdx.x - nblk_a1) * blockDim.x + threadIdx.x;
        int stride = 512 * blockDim.x;
        for (; i < E; i += stride) rank[i] = atomicAdd(&counts[seg[i]], 1);
    }
}

// ---- exclusive scan of counts -> offsets (single block) --------------------

__global__ void scan_kernel(const int* __restrict__ counts, int* __restrict__ offsets, int N) {
    __shared__ int part[1024];
    int tid = threadIdx.x;
    int per = (N + 1023) / 1024;
    int base = tid * per;
    int local[32];
    int sum = 0;
    for (int i = 0; i < per; ++i) {
        int idx = base + i;
        local[i] = sum;
        if (idx < N) sum += counts[idx];
    }
    part[tid] = sum;
    __syncthreads();
    for (int off = 1; off < 1024; off <<= 1) {
        int v = 0;
        if (tid >= off) v = part[tid - off];
        __syncthreads();
        if (tid >= off) part[tid] += v;
        __syncthreads();
    }
    int excl = (tid == 0) ? 0 : part[tid - 1];
    for (int i = 0; i < per; ++i) {
        int idx = base + i;
        if (idx < N) offsets[idx] = excl + local[i];
    }
    if (tid == 1023) offsets[N] = part[1023];
}

// ---- edge pass: pos = offsets[seg]+rank; a_csr[pos][h], elist[pos] ---------

__global__ __launch_bounds__(256) void edge_kernel(
    const float* __restrict__ meta, const float* __restrict__ w2,
    const float* __restrict__ a1, const int* __restrict__ seg,
    const int* __restrict__ rank, const int* __restrict__ offsets,
    float* __restrict__ a_csr, int* __restrict__ elist, int E)
{
    __shared__ float sm[64][68];      // celu(meta) tile, padded
    __shared__ float w2s[4][64];
    int t = threadIdx.x;
    w2s[t >> 6][t & 63] = w2[t];      // 256 == 4*64

    long e0 = (long)blockIdx.x * 64;
    const float4* msrc = (const float4*)meta + e0 * 16;
    int nval = (int)min((long)64, (long)E - e0);

#pragma unroll
    for (int k = 0; k < 4; ++k) {
        int j = t + k * 256;
        int e_loc = j >> 4, d4 = j & 15;
        if (e_loc < nval) {
            float4 v = msrc[j];
            float4 c;
            c.x = celu3(v.x); c.y = celu3(v.y); c.z = celu3(v.z); c.w = celu3(v.w);
            *(float4*)&sm[e_loc][d4 * 4] = c;
        }
    }
    __syncthreads();

    int e_loc = t >> 2, h = t & 3;
    if (e_loc >= nval) return;
    long e = e0 + e_loc;
    const float4* row = (const float4*)&sm[e_loc][0];
    const float4* wr  = (const float4*)&w2s[h][0];
    float acc = 0.0f;
#pragma unroll
    for (int d4 = 0; d4 < 16; ++d4) {
        float4 v = row[d4], w = wr[d4];
        acc += v.x * w.x + v.y * w.y + v.z * w.z + v.w * w.w;
    }
    int s = seg[e];
    int pos = offsets[s] + rank[e];
    float a = celu3(a1[s * 4 + h] + acc);
    a_csr[(long)pos * 4 + h] = a;
    if (h == 0) elist[pos] = (int)e;
}

// ---- softmax + weighted aggregate: one wave per node -----------------------

__global__ __launch_bounds__(256) void agg2_kernel(
    const float* __restrict__ meta, const int* __restrict__ offsets,
    const int* __restrict__ elist, const float4* __restrict__ a_csr,
    float* __restrict__ out, int N)
{
    int lane = threadIdx.x & 63;
    int wv = threadIdx.x >> 6;
    int n = blockIdx.x * 4 + wv;
    if (n >= N) return;

    int beg = offsets[n];
    int end = offsets[n + 1];
    int cnt = end - beg;

    float acc0 = 0.f, acc1 = 0.f, acc2 = 0.f, acc3 = 0.f;

    if (cnt > 0 && cnt <= 64) {
        // ---- fast path: lane = edge ----
        bool valid = lane < cnt;
        int idx = beg + lane;
        int eid_l = 0;
        float4 av = {-INFINITY, -INFINITY, -INFINITY, -INFINITY};
        if (valid) {
            eid_l = elist[idx];
            av = a_csr[idx];
        }
        float4 m;
        m.x = wave_max64(av.x); m.y = wave_max64(av.y);
        m.z = wave_max64(av.z); m.w = wave_max64(av.w);

        float e0 = valid ? __expf(av.x - m.x) : 0.f;
        float e1 = valid ? __expf(av.y - m.y) : 0.f;
        float e2 = valid ? __expf(av.z - m.z) : 0.f;
        float e3 = valid ? __expf(av.w - m.w) : 0.f;

        float4 den;
        den.x = wave_sum64(e0); den.y = wave_sum64(e1);
        den.z = wave_sum64(e2); den.w = wave_sum64(e3);

        float at0 = e0 * (1.0f / den.x);
        float at1 = e1 * (1.0f / den.y);
        float at2 = e2 * (1.0f / den.z);
        float at3 = e3 * (1.0f / den.w);

#pragma unroll 4
        for (int j = 0; j < cnt; ++j) {
            int eid = __builtin_amdgcn_readlane(eid_l, j);
            float b0 = bcast_f(at0, j);
            float b1 = bcast_f(at1, j);
            float b2 = bcast_f(at2, j);
            float b3 = bcast_f(at3, j);
            float eft = celu3(meta[(long)eid * 64 + lane]);
            acc0 = fmaf(b0, eft, acc0);
            acc1 = fmaf(b1, eft, acc1);
            acc2 = fmaf(b2, eft, acc2);
            acc3 = fmaf(b3, eft, acc3);
        }
    } else if (cnt > 64) {
        // ---- fallback: streaming two-phase ----
        float4 m = {-INFINITY, -INFINITY, -INFINITY, -INFINITY};
        for (int c = beg; c < end; c += 64) {
            int idx = c + lane;
            if (idx < end) {
                float4 av = a_csr[idx];
                m.x = fmaxf(m.x, av.x); m.y = fmaxf(m.y, av.y);
                m.z = fmaxf(m.z, av.z); m.w = fmaxf(m.w, av.w);
            }
        }
        m.x = wave_max64(m.x); m.y = wave_max64(m.y);
        m.z = wave_max64(m.z); m.w = wave_max64(m.w);

        float4 den = {0.f, 0.f, 0.f, 0.f};
        for (int j = beg; j < end; ++j) {
            float4 av = a_csr[j];
            float e0 = __expf(av.x - m.x), e1 = __expf(av.y - m.y);
            float e2 = __expf(av.z - m.z), e3 = __expf(av.w - m.w);
            den.x += e0; den.y += e1; den.z += e2; den.w += e3;
            int eid = elist[j];
            float eft = celu3(meta[(long)eid * 64 + lane]);
            acc0 = fmaf(e0, eft, acc0);
            acc1 = fmaf(e1, eft, acc1);
            acc2 = fmaf(e2, eft, acc2);
            acc3 = fmaf(e3, eft, acc3);
        }
        acc0 *= (1.0f / den.x); acc1 *= (1.0f / den.y);
        acc2 *= (1.0f / den.z); acc3 *= (1.0f / den.w);
    }

    long ob = (long)n * 256 + lane;
    out[ob]       = celu3(acc0);
    out[ob + 64]  = celu3(acc1);
    out[ob + 128] = celu3(acc2);
    out[ob + 192] = celu3(acc3);
}

// ---- launch ----------------------------------------------------------------

extern "C" void kernel_launch(void* const* d_in, const int* in_sizes, int n_in,
                              void* d_out, int out_size, void* d_ws, size_t ws_size,
                              hipStream_t stream)
{
    const float* feat = (const float*)d_in[0];
    const float* meta = (const float*)d_in[1];
    const float* w1   = (const float*)d_in[2];
    const float* w2   = (const float*)d_in[3];
    const int*   seg  = (const int*)d_in[4];
    float* out = (float*)d_out;

    int N = in_sizes[0] / 64;
    int E = in_sizes[4];

    float4* a_csr = (float4*)d_ws;                 // E float4
    float*  a1    = (float*)(a_csr + E);           // N*4
    int* counts   = (int*)(a1 + (size_t)N * 4);    // N
    int* offsets  = counts + N;                    // N+1
    int* rank     = offsets + N + 1;               // E
    int* elist    = rank + E;                      // E

    int nblk_a1 = (N + 3) / 4;

    zero_kernel<<<(N + 255) / 256, 256, 0, stream>>>(counts, N);
    rank_hist_a1_kernel<<<nblk_a1 + 512, 256, 0, stream>>>(seg, counts, rank, E, feat, w1, a1, N);
    scan_kernel<<<1, 1024, 0, stream>>>(counts, offsets, N);
    edge_kernel<<<(E + 63) / 64, 256, 0, stream>>>(meta, w2, a1, seg, rank, offsets, (float*)a_csr, elist, E);
    agg2_kernel<<<(N + 3) / 4, 256, 0, stream>>>(meta, offsets, elist, a_csr, out, N);
}